// Round 9
// baseline (179.358 us; speedup 1.0000x reference)
//
#include <hip/hip_runtime.h>
#include <hip/hip_fp16.h>
#include <math.h>

// Problem constants: B=8, T=64, R=100, TH=768, IH=1024, P=N=512
#define B_  8
#define T_  64
#define R_  100
#define TH_ 768
#define IH_ 1024
#define P_  512
#define N_  512

#define CTANH 2.88539008177792681f   // 2*log2(e): tanh(x) = 1 - 2/(1+exp2(CTANH*x))
#define MAGIC 0x13579BDFu            // != 0xAAAAAAAA poison
#define PADK 40

typedef short short8  __attribute__((ext_vector_type(8)));
typedef float floatx4 __attribute__((ext_vector_type(4)));

__device__ __forceinline__ ushort f2bf(float f) {
  union { float f; unsigned int u; } v; v.f = f;
  unsigned int r = v.u + 0x7FFFu + ((v.u >> 16) & 1u);   // RNE
  return (ushort)(r >> 16);
}

struct SharedMem {
  ushort As[4][64 * PADK];    // 20480 B
  ushort Bs[4][32 * PADK];    // 10240 B
  float  red[2][64 * 33];     // 16896 B   -> total 47616 B (1 block/CU fits)
};

// ---------------------------------------------------------------------------
// Phase-1 tile body: sk4 GEMM (proven since R6). 1024 thr = 4 k-splits x 4
// waves; tile 64m x 32n; bf16 MFMA; bias + exact GELU -> f16 * CTANH.
// ---------------------------------------------------------------------------
__device__ __forceinline__ void gemm_tile(
    SharedMem& shm, int ct, int rt,
    const float* __restrict__ encT, const float* __restrict__ Wq,
    const float* __restrict__ bq, __half* __restrict__ qout,
    const float* __restrict__ encI, const float* __restrict__ Wk,
    const float* __restrict__ bk, __half* __restrict__ kout) {
  const bool isQ = rt < 8;
  const float* __restrict__ X = isQ ? encT : encI;
  const float* __restrict__ W = isQ ? Wq : Wk;
  const float* __restrict__ bias = isQ ? bq : bk;
  __half* __restrict__ Y = isQ ? qout : kout;
  const int M    = isQ ? (B_ * T_) : (B_ * R_);
  const int KDIM = isQ ? TH_ : IH_;
  const int row0 = (isQ ? rt : (rt - 8)) * 64;
  const int col0 = ct * 32;
  const int kq   = KDIM >> 2;
  const int ntiles = kq / 32;              // 6 (Q) or 8 (K)

  const int tid = threadIdx.x;
  const int sp  = tid >> 8;
  const int t   = tid & 255;
  const int kbase = sp * kq;

  const int arow = t >> 2;
  const int akq  = (t & 3) * 8;
  const int arowc = min(row0 + arow, M - 1);
  const float* __restrict__ Xp = X + (size_t)arowc * KDIM + kbase + akq;

  const int bkp = (t >> 4) * 2;
  const int bn2 = (t & 15) * 2;
  const float* __restrict__ Wp = W + (size_t)(kbase + bkp) * N_ + col0 + bn2;

  const int wv = t >> 6;
  const int lane = t & 63;
  const int wm = wv * 16;
  const int l15 = lane & 15;
  const int q8  = (lane >> 4) * 8;
  const int q4  = (lane >> 4) * 4;

  floatx4 acc0 = {0.f,0.f,0.f,0.f}, acc1 = {0.f,0.f,0.f,0.f};

  float4 a0 = *(const float4*)(Xp);
  float4 a1 = *(const float4*)(Xp + 4);
  float2 b0 = *(const float2*)(Wp);
  float2 b1 = *(const float2*)(Wp + N_);

  for (int kt = 0; kt < ntiles; ++kt) {
    {
      short8 pk;
      pk[0] = (short)f2bf(a0.x); pk[1] = (short)f2bf(a0.y);
      pk[2] = (short)f2bf(a0.z); pk[3] = (short)f2bf(a0.w);
      pk[4] = (short)f2bf(a1.x); pk[5] = (short)f2bf(a1.y);
      pk[6] = (short)f2bf(a1.z); pk[7] = (short)f2bf(a1.w);
      *(short8*)&shm.As[sp][arow * PADK + akq] = pk;
    }
    {
      unsigned int p0 = (unsigned int)f2bf(b0.x) | ((unsigned int)f2bf(b1.x) << 16);
      unsigned int p1 = (unsigned int)f2bf(b0.y) | ((unsigned int)f2bf(b1.y) << 16);
      *(unsigned int*)&shm.Bs[sp][(bn2 + 0) * PADK + bkp] = p0;
      *(unsigned int*)&shm.Bs[sp][(bn2 + 1) * PADK + bkp] = p1;
    }
    __syncthreads();

    if (kt + 1 < ntiles) {
      const int kb = (kt + 1) * 32;
      a0 = *(const float4*)(Xp + kb);
      a1 = *(const float4*)(Xp + kb + 4);
      b0 = *(const float2*)(Wp + (size_t)kb * N_);
      b1 = *(const float2*)(Wp + (size_t)(kb + 1) * N_);
    }

    short8 af  = *(const short8*)&shm.As[sp][(wm + l15) * PADK + q8];
    short8 bf0 = *(const short8*)&shm.Bs[sp][(l15) * PADK + q8];
    short8 bf1 = *(const short8*)&shm.Bs[sp][(16 + l15) * PADK + q8];
    acc0 = __builtin_amdgcn_mfma_f32_16x16x32_bf16(af, bf0, acc0, 0, 0, 0);
    acc1 = __builtin_amdgcn_mfma_f32_16x16x32_bf16(af, bf1, acc1, 0, 0, 0);
    __syncthreads();
  }

  if (sp >= 2) {
    float* L = shm.red[sp - 2];
    #pragma unroll
    for (int j = 0; j < 4; ++j) {
      L[(wm + q4 + j) * 33 + l15]      = acc0[j];
      L[(wm + q4 + j) * 33 + 16 + l15] = acc1[j];
    }
  }
  __syncthreads();
  if (sp < 2) {
    const float* L = shm.red[sp];
    #pragma unroll
    for (int j = 0; j < 4; ++j) {
      acc0[j] += L[(wm + q4 + j) * 33 + l15];
      acc1[j] += L[(wm + q4 + j) * 33 + 16 + l15];
    }
  }
  __syncthreads();
  if (sp == 1) {
    float* L = shm.red[0];
    #pragma unroll
    for (int j = 0; j < 4; ++j) {
      L[(wm + q4 + j) * 33 + l15]      = acc0[j];
      L[(wm + q4 + j) * 33 + 16 + l15] = acc1[j];
    }
  }
  __syncthreads();
  if (sp == 0) {
    const float* L = shm.red[0];
    const float is2 = 0.70710678118654752f;
    const float bia0 = bias[col0 + l15];
    const float bia1 = bias[col0 + 16 + l15];
    #pragma unroll
    for (int j = 0; j < 4; ++j) {
      const int row = row0 + wm + q4 + j;
      if (row < M) {
        float v0 = acc0[j] + L[(wm + q4 + j) * 33 + l15] + bia0;
        float v1 = acc1[j] + L[(wm + q4 + j) * 33 + 16 + l15] + bia1;
        v0 = CTANH * 0.5f * v0 * (1.f + erff(v0 * is2));
        v1 = CTANH * 0.5f * v1 * (1.f + erff(v1 * is2));
        Y[(size_t)row * N_ + col0 + l15]      = __float2half(v0);
        Y[(size_t)row * N_ + col0 + 16 + l15] = __float2half(v1);
      }
    }
  }
}

// ---------------------------------------------------------------------------
// Phase-2 wave task: fuse_h body (proven since R6). One wave = one rg.
// ---------------------------------------------------------------------------
__device__ __forceinline__ void fuse_task(
    int bt, int rg, int lane,
    const __half* __restrict__ q, const __half* __restrict__ k,
    const float* __restrict__ w, const float* __restrict__ bscalar,
    const float* __restrict__ mask, float* __restrict__ out) {
  const int sub  = lane >> 4;
  const int pi   = lane & 15;
  const int r = rg * 4 + sub;
  const int b = bt >> 6;

  const __half* __restrict__ qp = q + (size_t)bt * P_ + pi * 8;
  const __half* __restrict__ kp = k + (size_t)(b * R_ + r) * P_ + pi * 8;
  const float* __restrict__ wp = w + pi * 8;

  float acc0 = 0.f, acc1 = 0.f;
  #pragma unroll
  for (int i = 0; i < 4; ++i) {
    union { float4 f; __half2 h[4]; } qu, ku;
    qu.f = *(const float4*)(qp + i * 128);
    ku.f = *(const float4*)(kp + i * 128);
    float4 w0 = *(const float4*)(wp + i * 128);
    float4 w1 = *(const float4*)(wp + i * 128 + 4);
    #pragma unroll
    for (int e = 0; e < 4; ++e) {
      __half2 s = __hadd2(qu.h[e], ku.h[e]);
      float x0 = __low2float(s);
      float x1 = __high2float(s);
      float d0 = __builtin_amdgcn_rcpf(1.f + __builtin_amdgcn_exp2f(x0));
      float d1 = __builtin_amdgcn_rcpf(1.f + __builtin_amdgcn_exp2f(x1));
      float s0 = fmaf(-2.f, d0, 1.f);
      float s1 = fmaf(-2.f, d1, 1.f);
      const float we0 = (e == 0) ? w0.x : (e == 1) ? w0.z : (e == 2) ? w1.x : w1.z;
      const float we1 = (e == 0) ? w0.y : (e == 1) ? w0.w : (e == 2) ? w1.y : w1.w;
      acc0 = fmaf(we0, s0, acc0);
      acc1 = fmaf(we1, s1, acc1);
    }
  }
  float acc = acc0 + acc1;
  #pragma unroll
  for (int off = 1; off < 16; off <<= 1) acc += __shfl_xor(acc, off, 64);

  if (pi == 0) {
    out[(size_t)bt * R_ + r] = acc + bscalar[0] + mask[(size_t)bt * R_ + r];
  }
}

// ---------------------------------------------------------------------------
// Single-dispatch fused pipeline: phase1 GEMMs -> software grid barrier ->
// phase2 fusion. Grid = 256 blocks x 1024 thr = exactly 1 block/CU, so all
// blocks are co-resident (16 waves <= 32/CU, LDS 47.6 KB <= 160, VGPR <= 128
// via launch_bounds) and the flag barrier cannot deadlock. Flags live in ws:
// re-poisoned to 0xAA every replay, so MAGIC compare needs no init dispatch.
// ---------------------------------------------------------------------------
__global__ __launch_bounds__(1024) void fused_all(
    const float* __restrict__ encT, const float* __restrict__ Wq,
    const float* __restrict__ bq,
    const float* __restrict__ encI, const float* __restrict__ Wk,
    const float* __restrict__ bk,
    const float* __restrict__ w, const float* __restrict__ bscalar,
    const float* __restrict__ mask,
    __half* __restrict__ q, __half* __restrict__ k,
    unsigned int* __restrict__ flags, float* __restrict__ out) {
  __shared__ SharedMem shm;

  // ---- phase 1: 336 tiles (16 ct x 21 rt) over 256 blocks ----
  for (int tile = blockIdx.x; tile < 336; tile += 256) {
    __syncthreads();
    gemm_tile(shm, tile & 15, tile >> 4,
              encT, Wq, bq, q, encI, Wk, bk, k);
  }

  // ---- grid barrier (release own flag, await all 256) ----
  __syncthreads();                       // all this block's stores complete
  if (threadIdx.x == 0) {
    __threadfence();                     // device-scope release (L2 wb)
    __hip_atomic_store(&flags[blockIdx.x], MAGIC,
                       __ATOMIC_RELEASE, __HIP_MEMORY_SCOPE_AGENT);
  }
  for (;;) {
    int my = 1;
    if (threadIdx.x < 256) {
      my = (__hip_atomic_load(&flags[threadIdx.x], __ATOMIC_RELAXED,
                              __HIP_MEMORY_SCOPE_AGENT) == MAGIC);
    }
    if (__syncthreads_count(my) == 1024) break;
    __builtin_amdgcn_s_sleep(4);
  }
  __threadfence();                       // device-scope acquire (inv stale)
  __syncthreads();

  // ---- phase 2: 12800 (bt,rg) wave-tasks over 4096 waves ----
  const int lane = threadIdx.x & 63;
  const int gw = blockIdx.x * 16 + (threadIdx.x >> 6);
  for (int task = gw; task < 12800; task += 4096) {
    const int bt = task / 25;
    const int rg = task - bt * 25;
    fuse_task(bt, rg, lane, q, k, w, bscalar, mask, out);
  }
}

// ---------------------------------------------------------------------------
extern "C" void kernel_launch(void* const* d_in, const int* in_sizes, int n_in,
                              void* d_out, int out_size, void* d_ws, size_t ws_size,
                              hipStream_t stream) {
  const float* encT = (const float*)d_in[0];
  const float* encI = (const float*)d_in[1];
  const float* mask = (const float*)d_in[2];
  const float* Wq   = (const float*)d_in[3];
  const float* bq   = (const float*)d_in[4];
  const float* Wk   = (const float*)d_in[5];
  const float* bk   = (const float*)d_in[6];
  const float* w    = (const float*)d_in[7];
  const float* bsc  = (const float*)d_in[8];
  float* out = (float*)d_out;

  __half* q = (__half*)d_ws;                       // [512,512] f16
  __half* k = q + (size_t)B_ * T_ * P_;            // [800,512] f16
  unsigned int* flags = (unsigned int*)(k + (size_t)B_ * R_ * P_);  // [256]

  fused_all<<<dim3(256), 1024, 0, stream>>>(encT, Wq, bq, encI, Wk, bk,
                                            w, bsc, mask, q, k, flags, out);
}

// Round 10
// 98.062 us; speedup vs baseline: 1.8290x; 1.8290x over previous
//
#include <hip/hip_runtime.h>
#include <hip/hip_fp16.h>
#include <math.h>

// Problem constants: B=8, T=64, R=100, TH=768, IH=1024, P=N=512
#define B_  8
#define T_  64
#define R_  100
#define TH_ 768
#define IH_ 1024
#define P_  512
#define N_  512

#define CTANH 2.88539008177792681f   // 2*log2(e): tanh(x) = 1 - 2/(1+exp2(CTANH*x))
#define PADK 40

typedef short short8  __attribute__((ext_vector_type(8)));
typedef float floatx4 __attribute__((ext_vector_type(4)));

__device__ __forceinline__ ushort f2bf(float f) {
  union { float f; unsigned int u; } v; v.f = f;
  unsigned int r = v.u + 0x7FFFu + ((v.u >> 16) & 1u);   // RNE
  return (ushort)(r >> 16);
}

// ---------------------------------------------------------------------------
// MFMA bf16 GEMM + bias + exact GELU -> f16 out (pre-scaled by CTANH).
// In-block split-K=4: 1024 threads = 4 splits x 4 waves. Tile 64m x 32n.
// BYTE-IDENTICAL to round 6 (best known: ~17 us by ledger algebra).
// ---------------------------------------------------------------------------
__global__ __launch_bounds__(1024) void mfma_linear_gelu_sk4(
    const float* __restrict__ encT, const float* __restrict__ Wq,
    const float* __restrict__ bq, __half* __restrict__ qout,
    const float* __restrict__ encI, const float* __restrict__ Wk,
    const float* __restrict__ bk, __half* __restrict__ kout) {
  const int rt = blockIdx.y;
  const bool isQ = rt < 8;
  const float* __restrict__ X = isQ ? encT : encI;
  const float* __restrict__ W = isQ ? Wq : Wk;
  const float* __restrict__ bias = isQ ? bq : bk;
  __half* __restrict__ Y = isQ ? qout : kout;
  const int M    = isQ ? (B_ * T_) : (B_ * R_);
  const int KDIM = isQ ? TH_ : IH_;
  const int row0 = (isQ ? rt : (rt - 8)) * 64;
  const int col0 = blockIdx.x * 32;
  const int kq   = KDIM >> 2;              // k-quarter: 192 or 256
  const int ntiles = kq / 32;              // 6 (Q) or 8 (K)

  __shared__ ushort As[4][64 * PADK];
  __shared__ ushort Bs[4][32 * PADK];
  __shared__ float  red[2][64 * 33];

  const int tid = threadIdx.x;
  const int sp  = tid >> 8;
  const int t   = tid & 255;
  const int kbase = sp * kq;

  const int arow = t >> 2;
  const int akq  = (t & 3) * 8;
  const int arowc = min(row0 + arow, M - 1);
  const float* __restrict__ Xp = X + (size_t)arowc * KDIM + kbase + akq;

  const int bkp = (t >> 4) * 2;
  const int bn2 = (t & 15) * 2;
  const float* __restrict__ Wp = W + (size_t)(kbase + bkp) * N_ + col0 + bn2;

  const int wv = t >> 6;
  const int lane = t & 63;
  const int wm = wv * 16;
  const int l15 = lane & 15;
  const int q8  = (lane >> 4) * 8;
  const int q4  = (lane >> 4) * 4;

  floatx4 acc0 = {0.f,0.f,0.f,0.f}, acc1 = {0.f,0.f,0.f,0.f};

  float4 a0 = *(const float4*)(Xp);
  float4 a1 = *(const float4*)(Xp + 4);
  float2 b0 = *(const float2*)(Wp);
  float2 b1 = *(const float2*)(Wp + N_);

  for (int kt = 0; kt < ntiles; ++kt) {
    {
      short8 pk;
      pk[0] = (short)f2bf(a0.x); pk[1] = (short)f2bf(a0.y);
      pk[2] = (short)f2bf(a0.z); pk[3] = (short)f2bf(a0.w);
      pk[4] = (short)f2bf(a1.x); pk[5] = (short)f2bf(a1.y);
      pk[6] = (short)f2bf(a1.z); pk[7] = (short)f2bf(a1.w);
      *(short8*)&As[sp][arow * PADK + akq] = pk;
    }
    {
      unsigned int p0 = (unsigned int)f2bf(b0.x) | ((unsigned int)f2bf(b1.x) << 16);
      unsigned int p1 = (unsigned int)f2bf(b0.y) | ((unsigned int)f2bf(b1.y) << 16);
      *(unsigned int*)&Bs[sp][(bn2 + 0) * PADK + bkp] = p0;
      *(unsigned int*)&Bs[sp][(bn2 + 1) * PADK + bkp] = p1;
    }
    __syncthreads();

    if (kt + 1 < ntiles) {
      const int kb = (kt + 1) * 32;
      a0 = *(const float4*)(Xp + kb);
      a1 = *(const float4*)(Xp + kb + 4);
      b0 = *(const float2*)(Wp + (size_t)kb * N_);
      b1 = *(const float2*)(Wp + (size_t)(kb + 1) * N_);
    }

    short8 af  = *(const short8*)&As[sp][(wm + l15) * PADK + q8];
    short8 bf0 = *(const short8*)&Bs[sp][(l15) * PADK + q8];
    short8 bf1 = *(const short8*)&Bs[sp][(16 + l15) * PADK + q8];
    acc0 = __builtin_amdgcn_mfma_f32_16x16x32_bf16(af, bf0, acc0, 0, 0, 0);
    acc1 = __builtin_amdgcn_mfma_f32_16x16x32_bf16(af, bf1, acc1, 0, 0, 0);
    __syncthreads();
  }

  if (sp >= 2) {
    float* L = red[sp - 2];
    #pragma unroll
    for (int j = 0; j < 4; ++j) {
      L[(wm + q4 + j) * 33 + l15]      = acc0[j];
      L[(wm + q4 + j) * 33 + 16 + l15] = acc1[j];
    }
  }
  __syncthreads();
  if (sp < 2) {
    const float* L = red[sp];
    #pragma unroll
    for (int j = 0; j < 4; ++j) {
      acc0[j] += L[(wm + q4 + j) * 33 + l15];
      acc1[j] += L[(wm + q4 + j) * 33 + 16 + l15];
    }
  }
  __syncthreads();
  if (sp == 1) {
    float* L = red[0];
    #pragma unroll
    for (int j = 0; j < 4; ++j) {
      L[(wm + q4 + j) * 33 + l15]      = acc0[j];
      L[(wm + q4 + j) * 33 + 16 + l15] = acc1[j];
    }
  }
  __syncthreads();
  if (sp == 0) {
    const float* L = red[0];
    const float is2 = 0.70710678118654752f;
    const float bia0 = bias[col0 + l15];
    const float bia1 = bias[col0 + 16 + l15];
    #pragma unroll
    for (int j = 0; j < 4; ++j) {
      const int row = row0 + wm + q4 + j;
      if (row < M) {
        float v0 = acc0[j] + L[(wm + q4 + j) * 33 + l15] + bia0;
        float v1 = acc1[j] + L[(wm + q4 + j) * 33 + 16 + l15] + bia1;
        v0 = CTANH * 0.5f * v0 * (1.f + erff(v0 * is2));
        v1 = CTANH * 0.5f * v1 * (1.f + erff(v1 * is2));
        Y[(size_t)row * N_ + col0 + l15]      = __float2half(v0);
        Y[(size_t)row * N_ + col0 + 16 + l15] = __float2half(v1);
      }
    }
  }
}

// ---------------------------------------------------------------------------
// Fusion, LOW-WORKGROUP-COUNT variant: 1024 wgs x 256 thr = 4096 waves; each
// wave grid-strides 3-4 (bt,rg) tasks. Task body identical to R6's fuse_h.
// w slice cached in registers ACROSS tasks; all 8 task loads hoisted ahead of
// the trans chain. Tests the wg-dispatch-rate hypothesis: 3584 wgs -> 1024.
// ---------------------------------------------------------------------------
__global__ __launch_bounds__(256) void fuse_lowwg(
    const __half* __restrict__ q, const __half* __restrict__ k,
    const float* __restrict__ w, const float* __restrict__ bscalar,
    const float* __restrict__ mask, float* __restrict__ out) {
  const int lane = threadIdx.x & 63;
  const int pi   = lane & 15;              // p-slice
  const int sub  = lane >> 4;              // r within group of 4
  const int gw   = blockIdx.x * 4 + (threadIdx.x >> 6);   // 0..4095

  // w slice: constant per lane, loaded once, reused across all tasks
  const float* __restrict__ wp = w + pi * 8;
  float4 wa[4], wb[4];
  #pragma unroll
  for (int i = 0; i < 4; ++i) {
    wa[i] = *(const float4*)(wp + i * 128);
    wb[i] = *(const float4*)(wp + i * 128 + 4);
  }
  const float bval = bscalar[0];

  for (int task = gw; task < 12800; task += 4096) {
    const int bt = task / 25;              // 0..511 (const-div -> mul/shift)
    const int rg = task - bt * 25;         // 0..24
    const int r  = rg * 4 + sub;           // 0..99
    const int b  = bt >> 6;

    const __half* __restrict__ qp = q + (size_t)bt * P_ + pi * 8;
    const __half* __restrict__ kp = k + ((size_t)(b * R_ + r) << 9) + pi * 8;

    // hoist all 8 loads ahead of the trans chain
    float4 qv[4], kv[4];
    #pragma unroll
    for (int i = 0; i < 4; ++i) {
      qv[i] = *(const float4*)(qp + i * 128);
      kv[i] = *(const float4*)(kp + i * 128);
    }

    float acc0 = 0.f, acc1 = 0.f;
    #pragma unroll
    for (int i = 0; i < 4; ++i) {
      union { float4 f; __half2 h[4]; } qu, ku;
      qu.f = qv[i];
      ku.f = kv[i];
      #pragma unroll
      for (int e = 0; e < 4; ++e) {
        __half2 s = __hadd2(qu.h[e], ku.h[e]);
        float x0 = __low2float(s);
        float x1 = __high2float(s);
        float d0 = __builtin_amdgcn_rcpf(1.f + __builtin_amdgcn_exp2f(x0));
        float d1 = __builtin_amdgcn_rcpf(1.f + __builtin_amdgcn_exp2f(x1));
        float s0 = fmaf(-2.f, d0, 1.f);
        float s1 = fmaf(-2.f, d1, 1.f);
        const float we0 = (e == 0) ? wa[i].x : (e == 1) ? wa[i].z
                         : (e == 2) ? wb[i].x : wb[i].z;
        const float we1 = (e == 0) ? wa[i].y : (e == 1) ? wa[i].w
                         : (e == 2) ? wb[i].y : wb[i].w;
        acc0 = fmaf(we0, s0, acc0);
        acc1 = fmaf(we1, s1, acc1);
      }
    }
    float acc = acc0 + acc1;
    #pragma unroll
    for (int off = 1; off < 16; off <<= 1) acc += __shfl_xor(acc, off, 64);

    if (pi == 0) {
      const size_t o = (size_t)bt * R_ + r;
      out[o] = acc + bval + mask[o];
    }
  }
}

// ---------------------------------------------------------------------------
extern "C" void kernel_launch(void* const* d_in, const int* in_sizes, int n_in,
                              void* d_out, int out_size, void* d_ws, size_t ws_size,
                              hipStream_t stream) {
  const float* encT = (const float*)d_in[0];
  const float* encI = (const float*)d_in[1];
  const float* mask = (const float*)d_in[2];
  const float* Wq   = (const float*)d_in[3];
  const float* bq   = (const float*)d_in[4];
  const float* Wk   = (const float*)d_in[5];
  const float* bk   = (const float*)d_in[6];
  const float* w    = (const float*)d_in[7];
  const float* bsc  = (const float*)d_in[8];
  float* out = (float*)d_out;

  __half* q = (__half*)d_ws;               // [512, 512] f16, CTANH-prescaled
  __half* k = q + (size_t)B_ * T_ * P_;    // [800, 512] f16, CTANH-prescaled

  dim3 grid(N_ / 32, 8 + 13);              // 336 blocks x 1024 threads
  mfma_linear_gelu_sk4<<<grid, 1024, 0, stream>>>(encT, Wq, bq, q,
                                                  encI, Wk, bk, k);

  fuse_lowwg<<<dim3(1024), 256, 0, stream>>>(q, k, w, bsc, mask, out);
}